// Round 8
// baseline (756.570 us; speedup 1.0000x reference)
//
#include <hip/hip_runtime.h>
#include <hip/hip_bf16.h>

#define T_TOK 2048
#define HDIM  2048
#define IDIM  1024
#define NE    16
#define NEX   17
#define NASSIGN (T_TOK*3)
#define TM    64

#define G1_NCT 16                   // IDIM/64
#define G2_NCT 32                   // HDIM/64
#define G1_NWG (TM*G1_NCT)          // 1024
#define G2_NWG (TM*G2_NCT)          // 2048

typedef __attribute__((ext_vector_type(8))) short bf16x8;
typedef __attribute__((ext_vector_type(4))) float f32x4;

#define WAITVM(N) asm volatile("s_waitcnt vmcnt(" #N ")" ::: "memory")
#define WAITLGKM  asm volatile("s_waitcnt lgkmcnt(0)" ::: "memory")
#define SCHEDB    __builtin_amdgcn_sched_barrier(0)
#define BARRIER   __builtin_amdgcn_s_barrier()

__device__ __forceinline__ unsigned short f2bf(float f) {
    union { float f; unsigned u; } v; v.f = f;
    unsigned r = v.u + 0x7fffu + ((v.u >> 16) & 1u);
    return (unsigned short)(r >> 16);
}
__device__ __forceinline__ unsigned pack2f(float a, float b) {
    __hip_bfloat162 h = __float22bfloat162_rn(float2{a, b});
    unsigned r;
    __builtin_memcpy(&r, &h, 4);
    return r;
}
__device__ __forceinline__ float fidx(const float4& v, int j) {
    return ((const float*)&v)[j];
}
// chunk swizzle within 128B LDS rows (rows of 64 bf16)
__device__ __forceinline__ int SW(int r) { return (r ^ (r >> 2)) & 7; }
__device__ __forceinline__ int lds_off(int row, int kelem) {
    return (row << 7) + ((((kelem >> 3) ^ SW(row))) << 4) + ((kelem & 7) << 1);
}
__device__ __forceinline__ f32x4 mfma16(bf16x8 a, bf16x8 b, f32x4 c) {
    return __builtin_amdgcn_mfma_f32_16x16x32_bf16(a, b, c, 0, 0, 0);
}
__device__ __forceinline__ void gload_lds16(const void* g, void* lds) {
    __builtin_amdgcn_global_load_lds(
        (const __attribute__((address_space(1))) unsigned*)g,
        (__attribute__((address_space(3))) unsigned*)lds, 16, 0, 0);
}

// ---------------- x fp32 -> bf16 ----------------
__global__ __launch_bounds__(256) void k_cvt(const float* __restrict__ x,
                                             unsigned short* __restrict__ xbf) {
    int i = blockIdx.x * 256 + threadIdx.x;
    float4 v = ((const float4*)x)[i];
    uint2 p{pack2f(v.x, v.y), pack2f(v.z, v.w)};
    ((uint2*)xbf)[i] = p;
}

// ---------------- Router ----------------
__global__ void k_router(const float* __restrict__ x, const float* __restrict__ Wr,
                         const float* __restrict__ bias, float* __restrict__ wtok,
                         int* __restrict__ idxtok, int* __restrict__ counts) {
    int t = blockIdx.x;
    int lane = threadIdx.x & 63;
    int wave = threadIdx.x >> 6;
    __shared__ float lg[NE];
    const float4* xr = (const float4*)(x + (size_t)t * HDIM);
    for (int e = wave; e < NE; e += 4) {
        const float4* wr = (const float4*)(Wr + (size_t)e * HDIM);
        float s = 0.f;
        for (int j = lane; j < HDIM / 4; j += 64) {
            float4 a = xr[j], b = wr[j];
            s += a.x*b.x + a.y*b.y + a.z*b.z + a.w*b.w;
        }
        #pragma unroll
        for (int d = 32; d; d >>= 1) s += __shfl_xor(s, d);
        if (lane == 0) lg[e] = s + bias[e];
    }
    __syncthreads();
    if (threadIdx.x == 0) {
        float m = lg[0];
        #pragma unroll
        for (int e = 1; e < NE; e++) m = fmaxf(m, lg[e]);
        float p[NE]; float S = 0.f;
        #pragma unroll
        for (int e = 0; e < NE; e++) { p[e] = expf(lg[e] - m); S += p[e]; }
        int i0 = 0;
        #pragma unroll
        for (int e = 1; e < NE; e++) if (p[e] > p[i0]) i0 = e;
        int i1 = (i0 == 0) ? 1 : 0;
        for (int e = 0; e < NE; e++) if (e != i0 && p[e] > p[i1]) i1 = e;
        float v0 = p[i0] / S, v1 = p[i1] / S;
        float wsum = v0 + v1 + 1e-9f;
        wtok[t*2+0] = v0 / wsum;
        wtok[t*2+1] = v1 / wsum;
        idxtok[t*2+0] = i0;
        idxtok[t*2+1] = i1;
        atomicAdd(&counts[i0], 1);
        atomicAdd(&counts[i1], 1);
    }
}

// ---------------- scan + tile work-list ----------------
__global__ void k_scan(const int* __restrict__ counts, int* __restrict__ offs,
                       int* __restrict__ cursor, int4* __restrict__ tiles) {
    if (threadIdx.x == 0) {
        int acc = 0;
        for (int e = 0; e < NEX; e++) {
            offs[e] = acc; cursor[e] = acc;
            acc += (e < NE) ? counts[e] : T_TOK;
        }
        offs[NEX] = acc;
        int nt = 0;
        for (int e = 0; e < NEX; e++) {
            for (int r = offs[e]; r < offs[e+1]; r += 128) {
                tiles[nt] = int4{r, min(128, offs[e+1] - r), e, 0};
                nt++;
            }
        }
        for (; nt < TM; nt++) tiles[nt] = int4{0, 0, 0, 0};
    }
}

__global__ void k_scatter(const int* __restrict__ idxtok, const float* __restrict__ wtok,
                          int* __restrict__ cursor, const int* __restrict__ offs,
                          int* __restrict__ rows, float* __restrict__ wrow) {
    int t = blockIdx.x * blockDim.x + threadIdx.x;
    if (t >= T_TOK) return;
    #pragma unroll
    for (int k = 0; k < 2; k++) {
        int e = idxtok[t*2+k];
        int pos = atomicAdd(&cursor[e], 1);
        rows[pos] = t;
        wrow[pos] = wtok[t*2+k];
    }
    int p16 = offs[NE] + t;
    rows[p16] = t;
    wrow[p16] = 1.0f;
}

// ---------------- GEMM1: act = w * silu(X@Wg) * (X@Wu) -> bf16 ----------------
// tile 128x64, BK=64, 512 thr (8 waves 2x4). LDS 48KB -> 3 blocks/CU.
// A double-buffered via global_load_lds DMA; Bs/Us single-buffered, fed by
// depth-2 register prefetch. Counted vmcnt: 6 VMEM ops in flight at barrier.
__global__ __launch_bounds__(512, 6) void k_gemm1(
        const unsigned short* __restrict__ xbf,
        const float* __restrict__ Wg, const float* __restrict__ Wu,
        const float* __restrict__ sWg, const float* __restrict__ sWu,
        const int4* __restrict__ tiles, const int* __restrict__ rows,
        const float* __restrict__ wrow, unsigned short* __restrict__ act) {
    int bid = blockIdx.x;
    int wg = (bid & 7) * (G1_NWG >> 3) + (bid >> 3);   // XCD-chunked
    int ti = wg & (TM - 1);
    int ct = wg >> 6;

    int4 tl = tiles[ti];
    int nrows = tl.y;
    if (nrows == 0) return;
    int rs = tl.x, e = tl.z;
    const float* wgp = (e < NE) ? Wg + (size_t)e * HDIM * IDIM : sWg;
    const float* wup = (e < NE) ? Wu + (size_t)e * HDIM * IDIM : sWu;
    int n0 = ct * 64;

    __shared__ unsigned short As[2][128 * 64];   // 32 KB
    __shared__ unsigned short Bs[64 * 64];       // 8 KB
    __shared__ unsigned short Us[64 * 64];       // 8 KB

    int tid = threadIdx.x;
    int l = tid & 63, w = tid >> 6;
    // A: pre-swizzled per-lane global source, linear LDS dest (wave-chunked)
    int ar0 = w * 8 + (l >> 3);
    int ar1 = 64 + ar0;
    int rr0 = rows[rs + min(ar0, nrows - 1)];
    int rr1 = rows[rs + min(ar1, nrows - 1)];
    const unsigned short* asrc0 = xbf + (size_t)rr0 * HDIM + (((l & 7) ^ SW(ar0)) << 3);
    const unsigned short* asrc1 = xbf + (size_t)rr1 * HDIM + (((l & 7) ^ SW(ar1)) << 3);

    // weights: 4 consecutive n at k-rows kb, kb+1 per matrix
    int n4 = (tid & 15) << 2;
    int kb = (tid >> 4) << 1;
    const float* gsrc = wgp + (size_t)kb * IDIM + n0 + n4;
    const float* usrc = wup + (size_t)kb * IDIM + n0 + n4;

    int wr = (w >> 2) << 6;
    int wc = (w & 3) << 4;
    int fr = l & 15;
    int fk = (l >> 4) << 3;

    float4 gR[2][2], uR[2][2];     // two register sets, depth-2 prefetch

    #define G1_LOADW(K0, S) do { \
        gR[S][0] = *(const float4*)(gsrc + (size_t)(K0) * IDIM); \
        gR[S][1] = *(const float4*)(gsrc + (size_t)(K0) * IDIM + IDIM); \
        uR[S][0] = *(const float4*)(usrc + (size_t)(K0) * IDIM); \
        uR[S][1] = *(const float4*)(usrc + (size_t)(K0) * IDIM + IDIM); \
    } while (0)

    #define G1_GLOADA(K0, B) do { \
        gload_lds16(asrc0 + (K0), (char*)As[B] + w * 1024); \
        gload_lds16(asrc1 + (K0), (char*)As[B] + 8192 + w * 1024); \
    } while (0)

    #define G1_WRITEW(S) do { \
        _Pragma("unroll") \
        for (int i = 0; i < 4; ++i) { \
            int n = n4 + i; \
            *(unsigned*)((char*)Bs + lds_off(n, kb)) = pack2f(fidx(gR[S][0],i), fidx(gR[S][1],i)); \
            *(unsigned*)((char*)Us + lds_off(n, kb)) = pack2f(fidx(uR[S][0],i), fidx(uR[S][1],i)); \
        } \
    } while (0)

    #define G1_MFMA(B) do { \
        _Pragma("unroll") \
        for (int kh = 0; kh < 2; ++kh) { \
            int kk = (kh << 5) + fk; \
            bf16x8 a[4], bg, bu; \
            _Pragma("unroll") \
            for (int m = 0; m < 4; ++m) \
                a[m] = *(const bf16x8*)((const char*)As[B] + lds_off(wr + m * 16 + fr, kk)); \
            bg = *(const bf16x8*)((const char*)Bs + lds_off(wc + fr, kk)); \
            bu = *(const bf16x8*)((const char*)Us + lds_off(wc + fr, kk)); \
            _Pragma("unroll") \
            for (int m = 0; m < 4; ++m) { \
                accg[m] = mfma16(a[m], bg, accg[m]); \
                accu[m] = mfma16(a[m], bu, accu[m]); \
            } \
        } \
    } while (0)

    // step k (SB = regset holding W(k+1), AB = k&1):
    //   MFMA(k); barrier; stage W(k+1); issue W(k+3)[4], A(k+2)[2];
    //   WAITVM(6) retires W(k+2)+A(k+1), leaves [W(k+3), A(k+2)] in flight.
    #define G1_STEP(K, SB, AB) do { \
        G1_MFMA(AB); \
        SCHEDB; \
        BARRIER; \
        SCHEDB; \
        G1_WRITEW(SB); \
        G1_LOADW(min(((K)+3)*64, KLAST), SB); \
        G1_GLOADA(min(((K)+2)*64, KLAST), AB); \
        SCHEDB; \
        WAITVM(6); \
        WAITLGKM; \
        BARRIER; \
        SCHEDB; \
    } while (0)

    f32x4 accg[4] = {}, accu[4] = {};
    const int NK = HDIM / 64;
    const int KLAST = (NK - 1) * 64;

    // prologue: establish invariant for k=0
    G1_LOADW(0, 0);          // W0 [4]
    G1_LOADW(64, 1);         // W1 [4] -> 8
    G1_GLOADA(0, 0);         // A0 [2] -> 10
    SCHEDB;
    WAITVM(6);               // retire W0; [W1, A0]
    SCHEDB;
    G1_WRITEW(0);            // stage W0
    G1_LOADW(128, 0);        // W2 [4] -> 10
    G1_GLOADA(64, 1);        // A1 [2] -> 12
    SCHEDB;
    WAITVM(6);               // retire W1, A0; leave [W2, A1]
    WAITLGKM;
    BARRIER;
    SCHEDB;

    for (int k = 0; k < NK; k += 2) {
        G1_STEP(k,     1, 0);
        G1_STEP(k + 1, 0, 1);
    }
    WAITVM(0);

    int crow = (l >> 4) << 2;
    int ccol = l & 15;
    #pragma unroll
    for (int m = 0; m < 4; ++m) {
        #pragma unroll
        for (int reg = 0; reg < 4; ++reg) {
            int r = wr + m * 16 + crow + reg;
            if (r < nrows) {
                float wv = wrow[rs + r];
                float g = accg[m][reg], u = accu[m][reg];
                act[(size_t)(rs + r) * IDIM + n0 + wc + ccol] =
                    f2bf(g / (1.f + __expf(-g)) * u * wv);
            }
        }
    }
    #undef G1_LOADW
    #undef G1_GLOADA
    #undef G1_WRITEW
    #undef G1_MFMA
    #undef G1_STEP
}

// ---------------- GEMM2: out[tok] += act @ Wd ----------------
// LDS 40KB exactly -> 4 blocks/CU, 32 waves/CU.
__global__ __launch_bounds__(512, 8) void k_gemm2(
        const unsigned short* __restrict__ act,
        const float* __restrict__ Wd, const float* __restrict__ sWd,
        const int4* __restrict__ tiles, const int* __restrict__ rows,
        float* __restrict__ out) {
    int bid = blockIdx.x;
    int wg = (bid & 7) * (G2_NWG >> 3) + (bid >> 3);
    int ti = wg & (TM - 1);
    int ct = wg >> 6;

    int4 tl = tiles[ti];
    int nrows = tl.y;
    if (nrows == 0) return;
    int rs = tl.x, e = tl.z;
    const float* wdp = (e < NE) ? Wd + (size_t)e * IDIM * HDIM : sWd;
    int n0 = ct * 64;

    __shared__ unsigned short As[2][128 * 64];   // 32 KB
    __shared__ unsigned short Bs[64 * 64];       // 8 KB

    int tid = threadIdx.x;
    int l = tid & 63, w = tid >> 6;
    int ar0 = w * 8 + (l >> 3);
    int ar1 = 64 + ar0;
    const unsigned short* asrc0 = act + (size_t)(rs + min(ar0, nrows - 1)) * IDIM + (((l & 7) ^ SW(ar0)) << 3);
    const unsigned short* asrc1 = act + (size_t)(rs + min(ar1, nrows - 1)) * IDIM + (((l & 7) ^ SW(ar1)) << 3);

    int n4 = (tid & 15) << 2;
    int kb = (tid >> 4) << 1;
    const float* dsrc = wdp + (size_t)kb * HDIM + n0 + n4;

    int wr = (w >> 2) << 6;
    int wc = (w & 3) << 4;
    int fr = l & 15;
    int fk = (l >> 4) << 3;

    float4 dR[2][2];

    #define G2_LOADW(K0, S) do { \
        dR[S][0] = *(const float4*)(dsrc + (size_t)(K0) * HDIM); \
        dR[S][1] = *(const float4*)(dsrc + (size_t)(K0) * HDIM + HDIM); \
    } while (0)

    #define G2_GLOADA(K0, B) do { \
        gload_lds16(asrc0 + (K0), (char*)As[B] + w * 1024); \
        gload_lds16(asrc1 + (K0), (char*)As[B] + 8192 + w * 1024); \
    } while (0)

    #define G2_WRITEW(S) do { \
        _Pragma("unroll") \
        for (int i = 0; i < 4; ++i) { \
            int n = n4 + i; \
            *(unsigned*)((char*)Bs + lds_off(n, kb)) = pack2f(fidx(dR[S][0],i), fidx(dR[S][1],i)); \
        } \
    } while (0)

    #define G2_MFMA(B) do { \
        _Pragma("unroll") \
        for (int kh = 0; kh < 2; ++kh) { \
            int kk = (kh << 5) + fk; \
            bf16x8 a[4], b; \
            _Pragma("unroll") \
            for (int m = 0; m < 4; ++m) \
                a[m] = *(const bf16x8*)((const char*)As[B] + lds_off(wr + m * 16 + fr, kk)); \
            b = *(const bf16x8*)((const char*)Bs + lds_off(wc + fr, kk)); \
            _Pragma("unroll") \
            for (int m = 0; m < 4; ++m) \
                acc[m] = mfma16(a[m], b, acc[m]); \
        } \
    } while (0)

    #define G2_STEP(K, SB, AB) do { \
        G2_MFMA(AB); \
        SCHEDB; \
        BARRIER; \
        SCHEDB; \
        G2_WRITEW(SB); \
        G2_LOADW(min(((K)+3)*64, KLAST), SB); \
        G2_GLOADA(min(((K)+2)*64, KLAST), AB); \
        SCHEDB; \
        WAITVM(4); \
        WAITLGKM; \
        BARRIER; \
        SCHEDB; \
    } while (0)

    f32x4 acc[4] = {};
    const int NK = IDIM / 64;
    const int KLAST = (NK - 1) * 64;

    G2_LOADW(0, 0);          // [2]
    G2_LOADW(64, 1);         // [2] -> 4
    G2_GLOADA(0, 0);         // [2] -> 6
    SCHEDB;
    WAITVM(4);               // retire W0; [W1, A0]
    SCHEDB;
    G2_WRITEW(0);
    G2_LOADW(128, 0);        // -> 6
    G2_GLOADA(64, 1);        // -> 8
    SCHEDB;
    WAITVM(4);               // retire W1, A0; leave [W2, A1]
    WAITLGKM;
    BARRIER;
    SCHEDB;

    for (int k = 0; k < NK; k += 2) {
        G2_STEP(k,     1, 0);
        G2_STEP(k + 1, 0, 1);
    }
    WAITVM(0);

    int crow = (l >> 4) << 2;
    int ccol = l & 15;
    #pragma unroll
    for (int m = 0; m < 4; ++m) {
        #pragma unroll
        for (int reg = 0; reg < 4; ++reg) {
            int r = wr + m * 16 + crow + reg;
            if (r < nrows) {
                atomicAdd(&out[(size_t)rows[rs + r] * HDIM + n0 + wc + ccol], acc[m][reg]);
            }
        }
    }
    #undef G2_LOADW
    #undef G2_GLOADA
    #undef G2_WRITEW
    #undef G2_MFMA
    #undef G2_STEP
}

extern "C" void kernel_launch(void* const* d_in, const int* in_sizes, int n_in,
                              void* d_out, int out_size, void* d_ws, size_t ws_size,
                              hipStream_t stream) {
    const float* x    = (const float*)d_in[0];
    const float* Wr   = (const float*)d_in[1];
    const float* bias = (const float*)d_in[2];
    const float* Wg   = (const float*)d_in[3];
    const float* Wu   = (const float*)d_in[4];
    const float* Wd   = (const float*)d_in[5];
    const float* sWg  = (const float*)d_in[6];
    const float* sWu  = (const float*)d_in[7];
    const float* sWd  = (const float*)d_in[8];
    float* out = (float*)d_out;

    char* p = (char*)d_ws;
    int*   counts = (int*)p;                 p += 256;
    int*   offs   = (int*)p;                 p += 256;
    int*   cursor = (int*)p;                 p += 256;
    int4*  tiles  = (int4*)p;                p += TM * sizeof(int4);
    int*   idxtok = (int*)p;                 p += (size_t)T_TOK * 2 * sizeof(int);
    float* wtok   = (float*)p;               p += (size_t)T_TOK * 2 * sizeof(float);
    int*   rows   = (int*)p;                 p += (size_t)NASSIGN * sizeof(int);
    float* wrow   = (float*)p;               p += (size_t)NASSIGN * sizeof(float);
    unsigned short* act = (unsigned short*)p; p += (size_t)NASSIGN * IDIM * sizeof(unsigned short);
    unsigned short* xbf = (unsigned short*)p; // 8.4MB

    hipMemsetAsync(counts, 0, 256, stream);
    hipMemsetAsync(d_out, 0, (size_t)out_size * sizeof(float), stream);

    k_cvt<<<dim3(T_TOK * HDIM / 1024), dim3(256), 0, stream>>>(x, xbf);
    k_router<<<dim3(T_TOK), dim3(256), 0, stream>>>(x, Wr, bias, wtok, idxtok, counts);
    k_scan<<<dim3(1), dim3(64), 0, stream>>>(counts, offs, cursor, tiles);
    k_scatter<<<dim3((T_TOK + 255) / 256), dim3(256), 0, stream>>>(idxtok, wtok, cursor, offs, rows, wrow);
    k_gemm1<<<dim3(G1_NWG), dim3(512), 0, stream>>>(xbf, Wg, Wu, sWg, sWu, tiles, rows, wrow, act);
    k_gemm2<<<dim3(G2_NWG), dim3(512), 0, stream>>>(act, Wd, sWd, tiles, rows, out);
}

// Round 9
// 438.940 us; speedup vs baseline: 1.7236x; 1.7236x over previous
//
#include <hip/hip_runtime.h>
#include <hip/hip_bf16.h>

#define T_TOK 2048
#define HDIM  2048
#define IDIM  1024
#define NE    16
#define NEX   17
#define NASSIGN (T_TOK*3)
#define TM    64                    // 128-row tiles: max 47 routed + 16 shared

#define G1_NWG (TM*16)              // 1024
#define G2_NWG (TM*32)              // 2048

typedef __attribute__((ext_vector_type(8))) short bf16x8;
typedef __attribute__((ext_vector_type(4))) float f32x4;

#define WAITVM0   asm volatile("s_waitcnt vmcnt(0)" ::: "memory")
#define WAITLGKM0 asm volatile("s_waitcnt lgkmcnt(0)" ::: "memory")
#define SCHEDB    __builtin_amdgcn_sched_barrier(0)
#define BARRIER   __builtin_amdgcn_s_barrier()

__device__ __forceinline__ unsigned short f2bf(float f) {
    union { float f; unsigned u; } v; v.f = f;
    unsigned r = v.u + 0x7fffu + ((v.u >> 16) & 1u);
    return (unsigned short)(r >> 16);
}
__device__ __forceinline__ unsigned pack2f(float a, float b) {
    __hip_bfloat162 h = __float22bfloat162_rn(float2{a, b});
    unsigned r;
    __builtin_memcpy(&r, &h, 4);
    return r;
}
__device__ __forceinline__ f32x4 mfma16(bf16x8 a, bf16x8 b, f32x4 c) {
    return __builtin_amdgcn_mfma_f32_16x16x32_bf16(a, b, c, 0, 0, 0);
}

// ---------------- x fp32 -> bf16 ----------------
__global__ __launch_bounds__(256) void k_cvt(const float* __restrict__ x,
                                             unsigned short* __restrict__ xbf) {
    int i = blockIdx.x * 256 + threadIdx.x;
    float4 v = ((const float4*)x)[i];
    uint2 p{pack2f(v.x, v.y), pack2f(v.z, v.w)};
    ((uint2*)xbf)[i] = p;
}

// ---------------- Router ----------------
__global__ void k_router(const float* __restrict__ x, const float* __restrict__ Wr,
                         const float* __restrict__ bias, float* __restrict__ wtok,
                         int* __restrict__ idxtok, int* __restrict__ counts) {
    int t = blockIdx.x;
    int lane = threadIdx.x & 63;
    int wave = threadIdx.x >> 6;
    __shared__ float lg[NE];
    const float4* xr = (const float4*)(x + (size_t)t * HDIM);
    for (int e = wave; e < NE; e += 4) {
        const float4* wr = (const float4*)(Wr + (size_t)e * HDIM);
        float s = 0.f;
        for (int j = lane; j < HDIM / 4; j += 64) {
            float4 a = xr[j], b = wr[j];
            s += a.x*b.x + a.y*b.y + a.z*b.z + a.w*b.w;
        }
        #pragma unroll
        for (int d = 32; d; d >>= 1) s += __shfl_xor(s, d);
        if (lane == 0) lg[e] = s + bias[e];
    }
    __syncthreads();
    if (threadIdx.x == 0) {
        float m = lg[0];
        #pragma unroll
        for (int e = 1; e < NE; e++) m = fmaxf(m, lg[e]);
        float p[NE]; float S = 0.f;
        #pragma unroll
        for (int e = 0; e < NE; e++) { p[e] = expf(lg[e] - m); S += p[e]; }
        int i0 = 0;
        #pragma unroll
        for (int e = 1; e < NE; e++) if (p[e] > p[i0]) i0 = e;
        int i1 = (i0 == 0) ? 1 : 0;
        for (int e = 0; e < NE; e++) if (e != i0 && p[e] > p[i1]) i1 = e;
        float v0 = p[i0] / S, v1 = p[i1] / S;
        float wsum = v0 + v1 + 1e-9f;
        wtok[t*2+0] = v0 / wsum;
        wtok[t*2+1] = v1 / wsum;
        idxtok[t*2+0] = i0;
        idxtok[t*2+1] = i1;
        atomicAdd(&counts[i0], 1);
        atomicAdd(&counts[i1], 1);
    }
}

// ---------------- scan + tile work-list ----------------
__global__ void k_scan(const int* __restrict__ counts, int* __restrict__ offs,
                       int* __restrict__ cursor, int4* __restrict__ tiles) {
    if (threadIdx.x == 0) {
        int acc = 0;
        for (int e = 0; e < NEX; e++) {
            offs[e] = acc; cursor[e] = acc;
            acc += (e < NE) ? counts[e] : T_TOK;
        }
        offs[NEX] = acc;
        int nt = 0;
        for (int e = 0; e < NEX; e++) {
            for (int r = offs[e]; r < offs[e+1]; r += 128) {
                tiles[nt] = int4{r, min(128, offs[e+1] - r), e, 0};
                nt++;
            }
        }
        for (; nt < TM; nt++) tiles[nt] = int4{0, 0, 0, 0};
    }
}

__global__ void k_scatter(const int* __restrict__ idxtok, const float* __restrict__ wtok,
                          int* __restrict__ cursor, const int* __restrict__ offs,
                          int* __restrict__ rows, float* __restrict__ wrow) {
    int t = blockIdx.x * blockDim.x + threadIdx.x;
    if (t >= T_TOK) return;
    #pragma unroll
    for (int k = 0; k < 2; k++) {
        int e = idxtok[t*2+k];
        int pos = atomicAdd(&cursor[e], 1);
        rows[pos] = t;
        wrow[pos] = wtok[t*2+k];
    }
    int p16 = offs[NE] + t;
    rows[p16] = t;
    wrow[p16] = 1.0f;
}

// ---------------- GEMM1: act = w * silu(X@Wg) * (X@Wu) -> bf16 ----------------
// tile 128x64, BK=32, NK=64, 512 thr (8 waves 4x2, wave-tile 32x32).
// A-frags straight from global (L2/LLC); only W tiles in LDS (dbuf, 80B rows).
// One s_barrier per K-step.
__global__ __launch_bounds__(512) void k_gemm1(
        const unsigned short* __restrict__ xbf,
        const float* __restrict__ Wg, const float* __restrict__ Wu,
        const float* __restrict__ sWg, const float* __restrict__ sWu,
        const int4* __restrict__ tiles, const int* __restrict__ rows,
        const float* __restrict__ wrow, unsigned short* __restrict__ act) {
    int bid = blockIdx.x;
    int wg = (bid & 7) * (G1_NWG >> 3) + (bid >> 3);   // XCD-chunked
    int ti = wg & (TM - 1);
    int ct = wg >> 6;

    int4 tl = tiles[ti];
    int nrows = tl.y;
    if (nrows == 0) return;
    int rs = tl.x, e = tl.z;
    const float* wgp = (e < NE) ? Wg + (size_t)e * HDIM * IDIM : sWg;
    const float* wup = (e < NE) ? Wu + (size_t)e * HDIM * IDIM : sWu;
    int n0 = ct * 64;

    __shared__ unsigned short Bs[2][64 * 40];   // [n][32k] rows padded to 80B
    __shared__ unsigned short Us[2][64 * 40];
    __shared__ int rloc[128];

    int tid = threadIdx.x;
    if (tid < 128) rloc[tid] = rows[rs + min(tid, nrows - 1)];
    __syncthreads();

    int l = tid & 63, w = tid >> 6;
    int wr = (w >> 1) << 5;      // 0,32,64,96
    int wc = (w & 1) << 5;       // 0,32
    int fr = l & 15;
    int fk = (l >> 4) << 3;      // 0,8,16,24

    const unsigned short* ap0 = xbf + (size_t)rloc[wr + fr] * HDIM + fk;
    const unsigned short* ap1 = xbf + (size_t)rloc[wr + 16 + fr] * HDIM + fk;

    // W staging: thread covers n2,n2+1 at k-rows kb,kb+1
    int n2 = (tid & 31) << 1;
    int kb = (tid >> 5) << 1;    // 0..30
    const float* gsrc = wgp + (size_t)kb * IDIM + n0 + n2;
    const float* usrc = wup + (size_t)kb * IDIM + n0 + n2;
    int wb0 = n2 * 80 + kb * 2;
    int wb1 = wb0 + 80;

    int ro0 = (wc + fr) * 80 + fk * 2;
    int ro1 = (wc + 16 + fr) * 80 + fk * 2;

    float2 g0, g1, u0, u1;
    bf16x8 aP0, aP1, aQ0, aQ1;
    f32x4 accg[2][2] = {}, accu[2][2] = {};

    const int NK = HDIM / 32;
    const int KL = (NK - 1) * 32;

    #define G1_LOADW(KE) do { \
        g0 = *(const float2*)(gsrc + (size_t)(KE) * IDIM); \
        g1 = *(const float2*)(gsrc + (size_t)(KE) * IDIM + IDIM); \
        u0 = *(const float2*)(usrc + (size_t)(KE) * IDIM); \
        u1 = *(const float2*)(usrc + (size_t)(KE) * IDIM + IDIM); \
    } while (0)
    #define G1_WRITEW(B) do { \
        *(unsigned*)((char*)Bs[B] + wb0) = pack2f(g0.x, g1.x); \
        *(unsigned*)((char*)Bs[B] + wb1) = pack2f(g0.y, g1.y); \
        *(unsigned*)((char*)Us[B] + wb0) = pack2f(u0.x, u1.x); \
        *(unsigned*)((char*)Us[B] + wb1) = pack2f(u0.y, u1.y); \
    } while (0)
    #define G1_COMPUTE(B, A0, A1) do { \
        bf16x8 b0 = *(const bf16x8*)((const char*)Bs[B] + ro0); \
        bf16x8 v0 = *(const bf16x8*)((const char*)Us[B] + ro0); \
        accg[0][0] = mfma16(A0, b0, accg[0][0]); \
        accg[1][0] = mfma16(A1, b0, accg[1][0]); \
        accu[0][0] = mfma16(A0, v0, accu[0][0]); \
        accu[1][0] = mfma16(A1, v0, accu[1][0]); \
        bf16x8 b1 = *(const bf16x8*)((const char*)Bs[B] + ro1); \
        bf16x8 v1 = *(const bf16x8*)((const char*)Us[B] + ro1); \
        accg[0][1] = mfma16(A0, b1, accg[0][1]); \
        accg[1][1] = mfma16(A1, b1, accg[1][1]); \
        accu[0][1] = mfma16(A0, v1, accu[0][1]); \
        accu[1][1] = mfma16(A1, v1, accu[1][1]); \
    } while (0)

    // prologue: W(0) staged in buf0; A(0)->P; W(1) in regs
    G1_LOADW(0);
    G1_WRITEW(0);            // compiler inserts vmcnt wait
    aP0 = *(const bf16x8*)(ap0);
    aP1 = *(const bf16x8*)(ap1);
    G1_LOADW(32);
    WAITLGKM0;
    BARRIER;
    SCHEDB;

    for (int k = 0; k < NK; k += 2) {
        {   // step k: A=P, read buf0, write buf1 (W(k+1))
            int kA = min(k + 1, NK - 1) * 32;
            int kW = min(k + 2, NK - 1) * 32;
            G1_WRITEW(1);
            aQ0 = *(const bf16x8*)(ap0 + kA);
            aQ1 = *(const bf16x8*)(ap1 + kA);
            G1_LOADW(kW);
            SCHEDB;
            G1_COMPUTE(0, aP0, aP1);
            SCHEDB;
            WAITLGKM0;
            BARRIER;
            SCHEDB;
        }
        {   // step k+1: A=Q, read buf1, write buf0 (W(k+2))
            int kA = min(k + 2, NK - 1) * 32;
            int kW = min(k + 3, NK - 1) * 32;
            G1_WRITEW(0);
            aP0 = *(const bf16x8*)(ap0 + kA);
            aP1 = *(const bf16x8*)(ap1 + kA);
            G1_LOADW(kW);
            SCHEDB;
            G1_COMPUTE(1, aQ0, aQ1);
            SCHEDB;
            WAITLGKM0;
            BARRIER;
            SCHEDB;
        }
    }
    WAITVM0;

    int crow = (l >> 4) << 2;
    int ccol = l & 15;
    #pragma unroll
    for (int m = 0; m < 2; ++m) {
        #pragma unroll
        for (int reg = 0; reg < 4; ++reg) {
            int r = wr + m * 16 + crow + reg;
            if (r < nrows) {
                float wv = wrow[rs + r];
                #pragma unroll
                for (int n = 0; n < 2; ++n) {
                    float g = accg[m][n][reg], u = accu[m][n][reg];
                    act[(size_t)(rs + r) * IDIM + n0 + wc + n * 16 + ccol] =
                        f2bf(g / (1.f + __expf(-g)) * u * wv);
                }
            }
        }
    }
    #undef G1_LOADW
    #undef G1_WRITEW
    #undef G1_COMPUTE
}

// ---------------- GEMM2: out[tok] += act @ Wd ----------------
// tile 128x64, BK=32, NK=32, 512 thr. A from act (global, LLC). W LDS dbuf.
__global__ __launch_bounds__(512) void k_gemm2(
        const unsigned short* __restrict__ act,
        const float* __restrict__ Wd, const float* __restrict__ sWd,
        const int4* __restrict__ tiles, const int* __restrict__ rows,
        float* __restrict__ out) {
    int bid = blockIdx.x;
    int wg = (bid & 7) * (G2_NWG >> 3) + (bid >> 3);
    int ti = wg & (TM - 1);
    int ct = wg >> 6;

    int4 tl = tiles[ti];
    int nrows = tl.y;
    if (nrows == 0) return;
    int rs = tl.x, e = tl.z;
    const float* wdp = (e < NE) ? Wd + (size_t)e * IDIM * HDIM : sWd;
    int n0 = ct * 64;

    __shared__ unsigned short Bs[2][64 * 40];

    int tid = threadIdx.x;
    int l = tid & 63, w = tid >> 6;
    int wr = (w >> 1) << 5;
    int wc = (w & 1) << 5;
    int fr = l & 15;
    int fk = (l >> 4) << 3;

    const unsigned short* ap0 = act + (size_t)(rs + min(wr + fr, nrows - 1)) * IDIM + fk;
    const unsigned short* ap1 = act + (size_t)(rs + min(wr + 16 + fr, nrows - 1)) * IDIM + fk;

    int n2 = (tid & 31) << 1;
    int kb = (tid >> 5) << 1;
    const float* dsrc = wdp + (size_t)kb * HDIM + n0 + n2;
    int wb0 = n2 * 80 + kb * 2;
    int wb1 = wb0 + 80;

    int ro0 = (wc + fr) * 80 + fk * 2;
    int ro1 = (wc + 16 + fr) * 80 + fk * 2;

    float2 d0, d1;
    bf16x8 aP0, aP1, aQ0, aQ1;
    f32x4 acc[2][2] = {};

    const int NK = IDIM / 32;

    #define G2_LOADW(KE) do { \
        d0 = *(const float2*)(dsrc + (size_t)(KE) * HDIM); \
        d1 = *(const float2*)(dsrc + (size_t)(KE) * HDIM + HDIM); \
    } while (0)
    #define G2_WRITEW(B) do { \
        *(unsigned*)((char*)Bs[B] + wb0) = pack2f(d0.x, d1.x); \
        *(unsigned*)((char*)Bs[B] + wb1) = pack2f(d0.y, d1.y); \
    } while (0)
    #define G2_COMPUTE(B, A0, A1) do { \
        bf16x8 b0 = *(const bf16x8*)((const char*)Bs[B] + ro0); \
        acc[0][0] = mfma16(A0, b0, acc[0][0]); \
        acc[1][0] = mfma16(A1, b0, acc[1][0]); \
        bf16x8 b1 = *(const bf16x8*)((const char*)Bs[B] + ro1); \
        acc[0][1] = mfma16(A0, b1, acc[0][1]); \
        acc[1][1] = mfma16(A1, b1, acc[1][1]); \
    } while (0)

    G2_LOADW(0);
    G2_WRITEW(0);
    aP0 = *(const bf16x8*)(ap0);
    aP1 = *(const bf16x8*)(ap1);
    G2_LOADW(32);
    WAITLGKM0;
    BARRIER;
    SCHEDB;

    for (int k = 0; k < NK; k += 2) {
        {
            int kA = min(k + 1, NK - 1) * 32;
            int kW = min(k + 2, NK - 1) * 32;
            G2_WRITEW(1);
            aQ0 = *(const bf16x8*)(ap0 + kA);
            aQ1 = *(const bf16x8*)(ap1 + kA);
            G2_LOADW(kW);
            SCHEDB;
            G2_COMPUTE(0, aP0, aP1);
            SCHEDB;
            WAITLGKM0;
            BARRIER;
            SCHEDB;
        }
        {
            int kA = min(k + 2, NK - 1) * 32;
            int kW = min(k + 3, NK - 1) * 32;
            G2_WRITEW(0);
            aP0 = *(const bf16x8*)(ap0 + kA);
            aP1 = *(const bf16x8*)(ap1 + kA);
            G2_LOADW(kW);
            SCHEDB;
            G2_COMPUTE(1, aQ0, aQ1);
            SCHEDB;
            WAITLGKM0;
            BARRIER;
            SCHEDB;
        }
    }
    WAITVM0;

    int crow = (l >> 4) << 2;
    int ccol = l & 15;
    #pragma unroll
    for (int m = 0; m < 2; ++m) {
        #pragma unroll
        for (int reg = 0; reg < 4; ++reg) {
            int r = wr + m * 16 + crow + reg;
            if (r < nrows) {
                size_t base = (size_t)rows[rs + r] * HDIM + n0 + wc + ccol;
                atomicAdd(&out[base], acc[m][0][reg]);
                atomicAdd(&out[base + 16], acc[m][1][reg]);
            }
        }
    }
    #undef G2_LOADW
    #undef G2_WRITEW
    #undef G2_COMPUTE
}

extern "C" void kernel_launch(void* const* d_in, const int* in_sizes, int n_in,
                              void* d_out, int out_size, void* d_ws, size_t ws_size,
                              hipStream_t stream) {
    const float* x    = (const float*)d_in[0];
    const float* Wr   = (const float*)d_in[1];
    const float* bias = (const float*)d_in[2];
    const float* Wg   = (const float*)d_in[3];
    const float* Wu   = (const float*)d_in[4];
    const float* Wd   = (const float*)d_in[5];
    const float* sWg  = (const float*)d_in[6];
    const float* sWu  = (const float*)d_in[7];
    const float* sWd  = (const float*)d_in[8];
    float* out = (float*)d_out;

    char* p = (char*)d_ws;
    int*   counts = (int*)p;                 p += 256;
    int*   offs   = (int*)p;                 p += 256;
    int*   cursor = (int*)p;                 p += 256;
    int4*  tiles  = (int4*)p;                p += TM * sizeof(int4);
    int*   idxtok = (int*)p;                 p += (size_t)T_TOK * 2 * sizeof(int);
    float* wtok   = (float*)p;               p += (size_t)T_TOK * 2 * sizeof(float);
    int*   rows   = (int*)p;                 p += (size_t)NASSIGN * sizeof(int);
    float* wrow   = (float*)p;               p += (size_t)NASSIGN * sizeof(float);
    unsigned short* act = (unsigned short*)p; p += (size_t)NASSIGN * IDIM * sizeof(unsigned short);
    unsigned short* xbf = (unsigned short*)p; // 8.4MB

    hipMemsetAsync(counts, 0, 256, stream);
    hipMemsetAsync(d_out, 0, (size_t)out_size * sizeof(float), stream);

    k_cvt<<<dim3(T_TOK * HDIM / 1024), dim3(256), 0, stream>>>(x, xbf);
    k_router<<<dim3(T_TOK), dim3(256), 0, stream>>>(x, Wr, bias, wtok, idxtok, counts);
    k_scan<<<dim3(1), dim3(64), 0, stream>>>(counts, offs, cursor, tiles);
    k_scatter<<<dim3((T_TOK + 255) / 256), dim3(256), 0, stream>>>(idxtok, wtok, cursor, offs, rows, wrow);
    k_gemm1<<<dim3(G1_NWG), dim3(512), 0, stream>>>(xbf, Wg, Wu, sWg, sWu, tiles, rows, wrow, act);
    k_gemm2<<<dim3(G2_NWG), dim3(512), 0, stream>>>(act, Wd, sWd, tiles, rows, out);
}